// Round 11
// baseline (710.144 us; speedup 1.0000x reference)
//
#include <hip/hip_runtime.h>

#define NN 1024
#define DFEAT 6
#define TSTEPS 60
#define HID 64
#define RREL 60
#define SENT -1.0e30f

typedef unsigned int uint4v __attribute__((ext_vector_type(4)));

// Single worker kernel (R10 stream/GRU bodies, proven codegen):
//  blocks [0,1024)    : GRU node n; epilogue writes s_i/s_j/s_f1/s_hw,
//                       release-fence, bumps gru_done.
//  blocks [1024,5120) : rel stream quarter-row; after temp write + release
//                       fence, bumps row_cnt[i]; the 4th arrival acquires
//                       gru_done==1024 (agent-scope spin; deadlock-free:
//                       GRU blocks are dispatched first and have no deps),
//                       then does the row softmax+dot+FC in-place.
__global__ __launch_bounds__(256) void fused_kernel(
    const float* __restrict__ x,      // (1024, 360)
    const float* __restrict__ W_ih,   // (192, 6)
    const float* __restrict__ W_hh,   // (192, 64)
    const float* __restrict__ b_ih,   // (192)
    const float* __restrict__ b_hh,   // (192)
    const float* __restrict__ w_att,  // (188)
    const float* __restrict__ b_att,  // (1)
    const float* __restrict__ W_fc,   // (128)
    const float* __restrict__ b_fc,   // (1)
    const float* __restrict__ rel,    // (1024, 1024, 60)
    unsigned int* __restrict__ ctrs,  // ws: [0..1023]=row_cnt, [1024]=gru_done
    float* __restrict__ s_i,          // ws (1024)
    float* __restrict__ s_j,          // ws (1024)
    float* __restrict__ s_f1,         // ws (1024): h_n . W_fc[0:64]
    float* __restrict__ s_hw,         // ws (1024): h_n . W_fc[64:128]
    float* __restrict__ temp,         // ws (1024,1024): srel or SENT
    float* __restrict__ out)          // (1024)
{
    const int tid = threadIdx.x;

    if (blockIdx.x >= NN) {
        // ---------------- rel stream part (R9/R10 proven body) ----------------
        const int b = blockIdx.x - NN;            // 0..4095
        const int i = b >> 2;
        const int j = ((b & 3) << 8) + tid;
        const size_t pair = (size_t)i * NN + j;

        {
            float wrel[RREL];                      // uniform
#pragma unroll
            for (int r = 0; r < RREL; ++r) wrel[r] = w_att[2 * HID + r];

            const uint4v* rp = reinterpret_cast<const uint4v*>(rel + pair * RREL);
            float srel = 0.0f;
            unsigned int mb = 0u;
#pragma unroll
            for (int k = 0; k < RREL / 4; ++k) {
                uint4v v = rp[k];
                srel += __uint_as_float(v.x) * wrel[4*k+0]
                      + __uint_as_float(v.y) * wrel[4*k+1]
                      + __uint_as_float(v.z) * wrel[4*k+2]
                      + __uint_as_float(v.w) * wrel[4*k+3];
                mb |= v.x | v.y | v.z | v.w;
            }
            temp[pair] = (mb != 0u) ? srel : SENT;
        }

        // release our 256 temp values, then count arrivals for row i
        __threadfence();
        __syncthreads();
        __shared__ int last_sh;
        if (tid == 0)
            last_sh = (atomicAdd(&ctrs[i], 1u) == 3u);
        __syncthreads();
        if (!last_sh) return;

        // -------- last block of row i: wait for GRU, then row phase --------
        if (tid == 0) {
            while (__hip_atomic_load(&ctrs[NN], __ATOMIC_ACQUIRE,
                                     __HIP_MEMORY_SCOPE_AGENT) < (unsigned)NN)
                __builtin_amdgcn_s_sleep(16);
            __threadfence();                       // acquire temp + s_* writes
        }
        __syncthreads();

        __shared__ float red_sh[256];
        __shared__ float red2_sh[256];

        const float si_b = s_i[i] + b_att[0];
        float4 sv = reinterpret_cast<const float4*>(temp + (size_t)i * NN)[tid];
        float4 sj = reinterpret_cast<const float4*>(s_j)[tid];

        float tvv[4];
        {
            float srels[4] = {sv.x, sv.y, sv.z, sv.w};
            float sjs[4]   = {sj.x, sj.y, sj.z, sj.w};
#pragma unroll
            for (int c = 0; c < 4; ++c) {
                float w = si_b + sjs[c] + srels[c];
                w = (w >= 0.0f) ? w : 0.01f * w;
                float tv = (srels[c] != SENT) ? w : 0.0f;   // mask * weight
                tvv[c] = (tv == 0.0f) ? -10000.0f : tv;
            }
        }
        float m = fmaxf(fmaxf(tvv[0], tvv[1]), fmaxf(tvv[2], tvv[3]));
        red_sh[tid] = m;
        __syncthreads();
        for (int s = 128; s > 0; s >>= 1) {
            if (tid < s) red_sh[tid] = fmaxf(red_sh[tid], red_sh[tid + s]);
            __syncthreads();
        }
        const float M = red_sh[0];
        __syncthreads();

        float4 hw4 = reinterpret_cast<const float4*>(s_hw)[tid];
        float lsum, pdot;
        {
            float e0 = __expf(tvv[0] - M), e1 = __expf(tvv[1] - M);
            float e2 = __expf(tvv[2] - M), e3 = __expf(tvv[3] - M);
            lsum = e0 + e1 + e2 + e3;              // denom over ALL j (reference)
            float p0 = (tvv[0] != -10000.0f) ? e0 : 0.0f;
            float p1 = (tvv[1] != -10000.0f) ? e1 : 0.0f;
            float p2 = (tvv[2] != -10000.0f) ? e2 : 0.0f;
            float p3 = (tvv[3] != -10000.0f) ? e3 : 0.0f;
            pdot = p0 * hw4.x + p1 * hw4.y + p2 * hw4.z + p3 * hw4.w;
        }
        red_sh[tid]  = lsum;
        red2_sh[tid] = pdot;
        __syncthreads();
        for (int s = 128; s > 0; s >>= 1) {
            if (tid < s) {
                red_sh[tid]  += red_sh[tid + s];
                red2_sh[tid] += red2_sh[tid + s];
            }
            __syncthreads();
        }
        if (tid == 0)
            out[i] = s_f1[i] + b_fc[0] + red2_sh[0] / red_sh[0];
        return;
    }

    // ---------------- GRU part (R10 proven body; h_last store dropped) -------
    const int n = blockIdx.x;
    const int g = tid;

    __shared__ __align__(16) float x_sh[DFEAT * TSTEPS];
    __shared__ __align__(16) float h_sh[HID];
    __shared__ float gi_sh[192];
    __shared__ float gh_sh[192];

    for (int idx = g; idx < DFEAT * TSTEPS; idx += 256)
        x_sh[idx] = x[(size_t)n * (DFEAT * TSTEPS) + idx];

    float whh[HID];
    float wih[DFEAT];
    float bih = 0.0f, bhh = 0.0f;
    if (g < 192) {
#pragma unroll
        for (int k4 = 0; k4 < HID / 4; ++k4) {
            float4 w = *reinterpret_cast<const float4*>(&W_hh[g * HID + k4 * 4]);
            whh[k4 * 4 + 0] = w.x; whh[k4 * 4 + 1] = w.y;
            whh[k4 * 4 + 2] = w.z; whh[k4 * 4 + 3] = w.w;
        }
#pragma unroll
        for (int d = 0; d < DFEAT; ++d) wih[d] = W_ih[g * DFEAT + d];
        bih = b_ih[g];
        bhh = b_hh[g];
    }

    if (g < HID) h_sh[g] = 0.0f;
    __syncthreads();

    for (int t = 0; t < TSTEPS; ++t) {
        if (g < 192) {
            float gi = bih;
#pragma unroll
            for (int d = 0; d < DFEAT; ++d) gi += x_sh[d * TSTEPS + t] * wih[d];

            float gh = bhh;
#pragma unroll
            for (int k4 = 0; k4 < HID / 4; ++k4) {
                float4 hv = *reinterpret_cast<const float4*>(&h_sh[k4 * 4]);
                gh += hv.x * whh[k4 * 4 + 0] + hv.y * whh[k4 * 4 + 1]
                    + hv.z * whh[k4 * 4 + 2] + hv.w * whh[k4 * 4 + 3];
            }
            gi_sh[g] = gi;
            gh_sh[g] = gh;
        }
        __syncthreads();

        if (g < HID) {
            float ir = gi_sh[g],        hr = gh_sh[g];
            float iz = gi_sh[HID + g],  hz = gh_sh[HID + g];
            float in_ = gi_sh[2*HID + g], hn = gh_sh[2*HID + g];
            float r = 1.0f / (1.0f + __expf(-(ir + hr)));
            float z = 1.0f / (1.0f + __expf(-(iz + hz)));
            float nn_ = tanhf(in_ + r * hn);
            float hold = h_sh[g];
            h_sh[g] = (1.0f - z) * nn_ + z * hold;
        }
        __syncthreads();
    }

    if (g < HID) {
        float hv = h_sh[g];
        float pi = hv * w_att[g];
        float pj = hv * w_att[HID + g];
        float f1 = hv * W_fc[g];
        float hw = hv * W_fc[HID + g];
#pragma unroll
        for (int off = 32; off > 0; off >>= 1) {
            pi += __shfl_down(pi, off);
            pj += __shfl_down(pj, off);
            f1 += __shfl_down(f1, off);
            hw += __shfl_down(hw, off);
        }
        if (g == 0) {
            s_i[n] = pi; s_j[n] = pj; s_f1[n] = f1; s_hw[n] = hw;
            __threadfence();                       // release s_* before signal
            atomicAdd(&ctrs[NN], 1u);
        }
    }
}

extern "C" void kernel_launch(void* const* d_in, const int* in_sizes, int n_in,
                              void* d_out, int out_size, void* d_ws, size_t ws_size,
                              hipStream_t stream) {
    const float* x     = (const float*)d_in[0];
    const float* rel   = (const float*)d_in[1];
    const float* W_ih  = (const float*)d_in[2];
    const float* W_hh  = (const float*)d_in[3];
    const float* b_ih  = (const float*)d_in[4];
    const float* b_hh  = (const float*)d_in[5];
    const float* w_att = (const float*)d_in[6];
    const float* b_att = (const float*)d_in[7];
    const float* W_fc  = (const float*)d_in[8];
    const float* b_fc  = (const float*)d_in[9];

    unsigned int* ctrs = (unsigned int*)d_ws;        // 1025 uints (pad to 1056)
    float* base  = (float*)d_ws + 1056;              // 16B-aligned
    float* s_i   = base;                             // 1024
    float* s_j   = base + NN;                        // 1024
    float* s_f1  = base + 2 * NN;                    // 1024
    float* s_hw  = base + 3 * NN;                    // 1024
    float* temp  = base + 4 * NN;                    // 1024*1024

    hipMemsetAsync(ctrs, 0, 1056 * sizeof(unsigned int), stream);
    fused_kernel<<<NN + NN * 4, 256, 0, stream>>>(
        x, W_ih, W_hh, b_ih, b_hh, w_att, b_att, W_fc, b_fc, rel,
        ctrs, s_i, s_j, s_f1, s_hw, temp, (float*)d_out);
}

// Round 12
// 87.995 us; speedup vs baseline: 8.0702x; 8.0702x over previous
//
#include <hip/hip_runtime.h>

#define NN 1024
#define DFEAT 6
#define TSTEPS 60
#define HID 64
#define RREL 60
#define SENT -1.0e30f

typedef unsigned int uint4v __attribute__((ext_vector_type(4)));

// R10 EXACT REVERT (best verified: 88.0us). Fused kernel: blocks [0,1024) =
// GRU; blocks [1024,5120) = rel stream (1 j-row/thread). GRU epilogue emits
// s_i/s_j plus f1[n] = h_n.W_fc[0:64] and hw[n] = h_n.W_fc[64:128]; the row
// kernel's agg matvec collapses to a 1024-length dot (W_fc.agg = invS *
// sum_j pm[j]*hw[j]). R8/R11 lesson: do NOT restructure the stream kernel
// (work-queues, device-scope fences, persistent phases all regress >5x).
__global__ __launch_bounds__(256) void fused_kernel(
    const float* __restrict__ x,      // (1024, 360)
    const float* __restrict__ W_ih,   // (192, 6)
    const float* __restrict__ W_hh,   // (192, 64)
    const float* __restrict__ b_ih,   // (192)
    const float* __restrict__ b_hh,   // (192)
    const float* __restrict__ w_att,  // (188)
    const float* __restrict__ W_fc,   // (128)
    const float* __restrict__ rel,    // (1024, 1024, 60)
    float* __restrict__ h_last,       // (1024, 64)
    float* __restrict__ s_i,          // (1024)
    float* __restrict__ s_j,          // (1024)
    float* __restrict__ s_f1,         // (1024): h_n . W_fc[0:64]
    float* __restrict__ s_hw,         // (1024): h_n . W_fc[64:128]
    float* __restrict__ temp)         // (1024, 1024): srel or SENT
{
    if (blockIdx.x >= NN) {
        // ---------------- rel stream part ----------------
        const int b = blockIdx.x - NN;            // 0..4095
        const int i = b >> 2;
        const int j = ((b & 3) << 8) + threadIdx.x;
        const size_t pair = (size_t)i * NN + j;

        float wrel[RREL];                          // uniform
#pragma unroll
        for (int r = 0; r < RREL; ++r) wrel[r] = w_att[2 * HID + r];

        const uint4v* rp = reinterpret_cast<const uint4v*>(rel + pair * RREL);
        float srel = 0.0f;
        unsigned int mb = 0u;
#pragma unroll
        for (int k = 0; k < RREL / 4; ++k) {
            uint4v v = rp[k];
            srel += __uint_as_float(v.x) * wrel[4*k+0]
                  + __uint_as_float(v.y) * wrel[4*k+1]
                  + __uint_as_float(v.z) * wrel[4*k+2]
                  + __uint_as_float(v.w) * wrel[4*k+3];
            mb |= v.x | v.y | v.z | v.w;
        }
        temp[pair] = (mb != 0u) ? srel : SENT;
        return;
    }

    // ---------------- GRU part ----------------
    const int n = blockIdx.x;
    const int g = threadIdx.x;

    __shared__ __align__(16) float x_sh[DFEAT * TSTEPS];
    __shared__ __align__(16) float h_sh[HID];
    __shared__ float gi_sh[192];
    __shared__ float gh_sh[192];

    for (int idx = g; idx < DFEAT * TSTEPS; idx += 256)
        x_sh[idx] = x[(size_t)n * (DFEAT * TSTEPS) + idx];

    float whh[HID];
    float wih[DFEAT];
    float bih = 0.0f, bhh = 0.0f;
    if (g < 192) {
#pragma unroll
        for (int k4 = 0; k4 < HID / 4; ++k4) {
            float4 w = *reinterpret_cast<const float4*>(&W_hh[g * HID + k4 * 4]);
            whh[k4 * 4 + 0] = w.x; whh[k4 * 4 + 1] = w.y;
            whh[k4 * 4 + 2] = w.z; whh[k4 * 4 + 3] = w.w;
        }
#pragma unroll
        for (int d = 0; d < DFEAT; ++d) wih[d] = W_ih[g * DFEAT + d];
        bih = b_ih[g];
        bhh = b_hh[g];
    }

    if (g < HID) h_sh[g] = 0.0f;
    __syncthreads();

    for (int t = 0; t < TSTEPS; ++t) {
        if (g < 192) {
            float gi = bih;
#pragma unroll
            for (int d = 0; d < DFEAT; ++d) gi += x_sh[d * TSTEPS + t] * wih[d];

            float gh = bhh;
#pragma unroll
            for (int k4 = 0; k4 < HID / 4; ++k4) {
                float4 hv = *reinterpret_cast<const float4*>(&h_sh[k4 * 4]);
                gh += hv.x * whh[k4 * 4 + 0] + hv.y * whh[k4 * 4 + 1]
                    + hv.z * whh[k4 * 4 + 2] + hv.w * whh[k4 * 4 + 3];
            }
            gi_sh[g] = gi;
            gh_sh[g] = gh;
        }
        __syncthreads();

        if (g < HID) {
            float ir = gi_sh[g],        hr = gh_sh[g];
            float iz = gi_sh[HID + g],  hz = gh_sh[HID + g];
            float in_ = gi_sh[2*HID + g], hn = gh_sh[2*HID + g];
            float r = 1.0f / (1.0f + __expf(-(ir + hr)));
            float z = 1.0f / (1.0f + __expf(-(iz + hz)));
            float nn_ = tanhf(in_ + r * hn);
            float hold = h_sh[g];
            h_sh[g] = (1.0f - z) * nn_ + z * hold;
        }
        __syncthreads();
    }

    if (g < HID) {
        float hv = h_sh[g];
        h_last[(size_t)n * HID + g] = hv;
        float pi = hv * w_att[g];
        float pj = hv * w_att[HID + g];
        float f1 = hv * W_fc[g];
        float hw = hv * W_fc[HID + g];
#pragma unroll
        for (int off = 32; off > 0; off >>= 1) {
            pi += __shfl_down(pi, off);
            pj += __shfl_down(pj, off);
            f1 += __shfl_down(f1, off);
            hw += __shfl_down(hw, off);
        }
        if (g == 0) { s_i[n] = pi; s_j[n] = pj; s_f1[n] = f1; s_hw[n] = hw; }
    }
}

// --------- Kernel 2: softmax + collapsed dot + FC (no h_last matvec) ---------
__global__ __launch_bounds__(256) void row_kernel(
    const float* __restrict__ temp,   // (1024, 1024): srel or SENT
    const float* __restrict__ s_i,    // (1024)
    const float* __restrict__ s_j,    // (1024)
    const float* __restrict__ s_f1,   // (1024)
    const float* __restrict__ s_hw,   // (1024)
    const float* __restrict__ b_att,  // (1)
    const float* __restrict__ b_fc,   // (1)
    float* __restrict__ out)          // (1024)
{
    const int i = blockIdx.x;
    const int tid = threadIdx.x;

    __shared__ float red_sh[256];
    __shared__ float red2_sh[256];

    const float si_b = s_i[i] + b_att[0];
    float4 sv = reinterpret_cast<const float4*>(temp + (size_t)i * NN)[tid];
    float4 sj = reinterpret_cast<const float4*>(s_j)[tid];

    float tvv[4];
    {
        float srels[4] = {sv.x, sv.y, sv.z, sv.w};
        float sjs[4]   = {sj.x, sj.y, sj.z, sj.w};
#pragma unroll
        for (int c = 0; c < 4; ++c) {
            float w = si_b + sjs[c] + srels[c];
            w = (w >= 0.0f) ? w : 0.01f * w;
            float tv = (srels[c] != SENT) ? w : 0.0f;   // mask * weight
            tvv[c] = (tv == 0.0f) ? -10000.0f : tv;
        }
    }
    float m = fmaxf(fmaxf(tvv[0], tvv[1]), fmaxf(tvv[2], tvv[3]));
    red_sh[tid] = m;
    __syncthreads();
    for (int s = 128; s > 0; s >>= 1) {
        if (tid < s) red_sh[tid] = fmaxf(red_sh[tid], red_sh[tid + s]);
        __syncthreads();
    }
    const float M = red_sh[0];
    __syncthreads();

    // exp, denominator over ALL j (reference semantics), masked numerator dot hw
    float4 hw4 = reinterpret_cast<const float4*>(s_hw)[tid];
    float lsum, pdot;
    {
        float e0 = __expf(tvv[0] - M), e1 = __expf(tvv[1] - M);
        float e2 = __expf(tvv[2] - M), e3 = __expf(tvv[3] - M);
        lsum = e0 + e1 + e2 + e3;
        float p0 = (tvv[0] != -10000.0f) ? e0 : 0.0f;
        float p1 = (tvv[1] != -10000.0f) ? e1 : 0.0f;
        float p2 = (tvv[2] != -10000.0f) ? e2 : 0.0f;
        float p3 = (tvv[3] != -10000.0f) ? e3 : 0.0f;
        pdot = p0 * hw4.x + p1 * hw4.y + p2 * hw4.z + p3 * hw4.w;
    }
    red_sh[tid]  = lsum;
    red2_sh[tid] = pdot;
    __syncthreads();
    for (int s = 128; s > 0; s >>= 1) {
        if (tid < s) {
            red_sh[tid]  += red_sh[tid + s];
            red2_sh[tid] += red2_sh[tid + s];
        }
        __syncthreads();
    }
    if (tid == 0)
        out[i] = s_f1[i] + b_fc[0] + red2_sh[0] / red_sh[0];
}

extern "C" void kernel_launch(void* const* d_in, const int* in_sizes, int n_in,
                              void* d_out, int out_size, void* d_ws, size_t ws_size,
                              hipStream_t stream) {
    const float* x     = (const float*)d_in[0];
    const float* rel   = (const float*)d_in[1];
    const float* W_ih  = (const float*)d_in[2];
    const float* W_hh  = (const float*)d_in[3];
    const float* b_ih  = (const float*)d_in[4];
    const float* b_hh  = (const float*)d_in[5];
    const float* w_att = (const float*)d_in[6];
    const float* b_att = (const float*)d_in[7];
    const float* W_fc  = (const float*)d_in[8];
    const float* b_fc  = (const float*)d_in[9];

    float* ws     = (float*)d_ws;
    float* h_last = ws;                          // 1024*64
    float* s_i    = ws + NN * HID;               // 1024
    float* s_j    = ws + NN * HID + NN;          // 1024
    float* s_f1   = ws + NN * HID + 2 * NN;      // 1024
    float* s_hw   = ws + NN * HID + 3 * NN;      // 1024
    float* temp   = ws + NN * HID + 4 * NN;      // 1024*1024

    fused_kernel<<<NN + NN * 4, 256, 0, stream>>>(
        x, W_ih, W_hh, b_ih, b_hh, w_att, W_fc, rel,
        h_last, s_i, s_j, s_f1, s_hw, temp);
    row_kernel<<<NN, 256, 0, stream>>>(temp, s_i, s_j, s_f1, s_hw,
                                       b_att, b_fc, (float*)d_out);
}